// Round 13
// baseline (2382.731 us; speedup 1.0000x reference)
//
#include <hip/hip_runtime.h>
#include <cstdint>

typedef _Float16 half8 __attribute__((ext_vector_type(8)));
typedef float floatx4 __attribute__((ext_vector_type(4)));
typedef unsigned long long u64;
typedef unsigned int u32;
typedef unsigned short u16;

#define NB 2048
#define NT 512
#define NH 256
#define NOUT 512

#define LOG2E 1.4426950408889634f
#define TWOL  2.8853900817779268f

__device__ __forceinline__ float fexp2(float x){ return __builtin_amdgcn_exp2f(x); }
__device__ __forceinline__ float frcp(float x){ return __builtin_amdgcn_rcpf(x); }

__device__ __forceinline__ floatx4 mfma16(half8 a, half8 b, floatx4 c) {
    return __builtin_amdgcn_mfma_f32_16x16x32_f16(a, b, c, 0, 0, 0);
}

// ----------------------------------------------------------------- prep ----
// blocks 0..1023: 32x32 transpose tiles of x -> xT ;  blocks 1024..1279: f16 packs.
// GATE-SCALE FOLDING (r12): rows 512..767 (g) x +2*LOG2E, others (i,f,o) x -LOG2E,
// so the pointwise computes exp2(p) directly.
__global__ void prep_kernel(const float* __restrict__ x, const float* __restrict__ Whh,
                            const float* __restrict__ Wlin, _Float16* __restrict__ Wpack,
                            _Float16* __restrict__ WlinPack, float* __restrict__ xT)
{
    const int b = blockIdx.x;
    if (b < 1024) {
        __shared__ float tile[32][33];
        const int tx = threadIdx.x & 31, ty = threadIdx.x >> 5;
        const int t0 = (b & 15) * 32;
        const int b0 = (b >> 4) * 32;
        #pragma unroll
        for (int i = 0; i < 4; i++)
            tile[ty + 8 * i][tx] = x[(size_t)(b0 + ty + 8 * i) * NT + t0 + tx];
        __syncthreads();
        #pragma unroll
        for (int i = 0; i < 4; i++)
            xT[(size_t)(t0 + ty + 8 * i) * NB + b0 + tx] = tile[tx][ty + 8 * i];
    } else {
        const int i = (b - 1024) * 256 + threadIdx.x;
        const int stride = 256 * 256;
        for (int k = i; k < 1024 * 256; k += stride) {
            const int row = k >> 8;
            const float s = (row >= 512 && row < 768) ? TWOL : -LOG2E;
            Wpack[k] = (_Float16)(s * Whh[k]);
        }
        for (int k = i; k < 512 * 256;  k += stride) WlinPack[k] = (_Float16)Wlin[k];
    }
}

// ----------------------------------------------------------------- lstm ----
// 128 blocks x 512 threads (8 waves, 2 waves/SIMD). Block: 16 rows, full 256 units.
// Wave wv: units [wv*32,+32) = 2 ug x 16 units x 4 gates; i,f,g register-resident
// (192 regs); r13: o-gate STREAMED FROM L2 per step (was LDS) - the 16 b128 LDS
// reads/wave/step move to the idle VMEM pipe with identical register lifetimes;
// Wpack is L2-resident (512KB/XCD). DS pipe/CU-step: ~3400 -> ~1900 cyc.
// r13b: lane^1 h-pack via quad_perm DPP (VALU) instead of __shfl_xor
// (ds_bpermute - 8 more DS ops/thread-step).
// K-major LDS h layout (r7), static ping-pong + 2-step unroll (r12).
// FUSED=1: linear layer fused in epilogue from h_T (in hA after 512 steps).
template<int FUSED>
__global__ __launch_bounds__(512, 1)
void lstm_kernel(const float* __restrict__ xT, const float* __restrict__ Wih,
                 const float* __restrict__ bih, const float* __restrict__ bhh,
                 const _Float16* __restrict__ Wpack, const _Float16* __restrict__ WlinPack,
                 const float* __restrict__ blin, float* __restrict__ outp,
                 u16* __restrict__ hlast)
{
    __shared__ __align__(16) u16 hA[4096];         // 8 KB  h (even t source)
    __shared__ __align__(16) u16 hB[4096];         // 8 KB  h (odd t source)
    __shared__ float2 bwlds[1024];                 // 8 KB  {scaled bias, scaled W_ih}

    const int tid  = threadIdx.x;
    const int lane = tid & 63;
    const int wv   = tid >> 6;     // 0..7
    const int l15  = lane & 15;
    const int l4   = lane >> 4;
    const int r0   = blockIdx.x * 16;
    const int u0   = wv * 32;

    // ---- prologue ----
    for (int g = tid; g < 1024; g += 512) {
        const float s = (g >= 512 && g < 768) ? TWOL : -LOG2E;
        bwlds[g] = make_float2(s * (bih[g] + bhh[g]), s * Wih[g]);
    }
    for (int i = tid; i < 1024; i += 512) ((u64*)hA)[i] = 0;   // h_0 = 0

    // register-resident W tiles: ug x {i,f,g}
    half8 wreg[2][3][8];
    #pragma unroll
    for (int ug = 0; ug < 2; ug++)
        #pragma unroll
        for (int q = 0; q < 3; q++) {
            const int G = q * 256 + u0 + ug * 16 + l15;
            #pragma unroll
            for (int kc = 0; kc < 8; kc++)
                wreg[ug][q][kc] = *(const half8*)(Wpack + (size_t)G * NH + kc * 32 + l4 * 8);
        }

    // per-lane o-gate source rows in Wpack (L2-resident)
    const _Float16* obase0 = Wpack + (size_t)(768 + u0 + 0 * 16 + l15) * NH + l4 * 8;
    const _Float16* obase1 = Wpack + (size_t)(768 + u0 + 1 * 16 + l15) * NH + l4 * 8;

    float cst[8];
    #pragma unroll
    for (int i = 0; i < 8; i++) cst[i] = 0.f;

    __syncthreads();

    // one timestep: read hsrc, write hdst (distinct static arrays per call site)
    auto step = [&](int t, const u16* hsrc, u16* hdst) {
        // issued at step head, consumed only in the pointwise tails
        const floatx4 xv = *(const floatx4*)(xT + (size_t)t * NB + r0 + l4 * 4);

        #pragma unroll
        for (int ug = 0; ug < 2; ug++) {
            const _Float16* ob = ug ? obase1 : obase0;
            floatx4 acc[4];
            #pragma unroll
            for (int q = 0; q < 4; q++)
                acc[q] = (floatx4){0.f, 0.f, 0.f, 0.f};

            __builtin_amdgcn_s_setprio(1);
            #pragma unroll
            for (int half_ = 0; half_ < 2; half_++) {
                // o-gate fragments: global loads from L2 (VMEM pipe), issued first
                half8 og[4];
                #pragma unroll
                for (int k2 = 0; k2 < 4; k2++)
                    og[k2] = *(const half8*)(ob + (half_ * 4 + k2) * 32);
                half8 a[4];
                #pragma unroll
                for (int k2 = 0; k2 < 4; k2++) {
                    const int kc = half_ * 4 + k2;
                    a[k2] = *(const half8*)(hsrc + (kc * 4 + l4) * 128 + l15 * 8);
                }
                #pragma unroll
                for (int k2 = 0; k2 < 4; k2++) {
                    const int kc = half_ * 4 + k2;
                    acc[0] = mfma16(a[k2], wreg[ug][0][kc], acc[0]);
                    acc[1] = mfma16(a[k2], wreg[ug][1][kc], acc[1]);
                    acc[2] = mfma16(a[k2], wreg[ug][2][kc], acc[2]);
                    acc[3] = mfma16(a[k2], og[k2],          acc[3]);
                }
            }
            __builtin_amdgcn_s_setprio(0);

            // scaled bias + x*W_ih in the tail; pointwise is exp2(p) directly
            float2 bw[4];
            #pragma unroll
            for (int q = 0; q < 4; q++) bw[q] = bwlds[q * 256 + u0 + ug * 16 + l15];

            #pragma unroll
            for (int j = 0; j < 4; j++) {
                const float pi = acc[0][j] + bw[0].x + xv[j] * bw[0].y;  // = -LOG2E * raw
                const float pf = acc[1][j] + bw[1].x + xv[j] * bw[1].y;
                const float pg = acc[2][j] + bw[2].x + xv[j] * bw[2].y;  // = +TWOL * raw
                const float po = acc[3][j] + bw[3].x + xv[j] * bw[3].y;
                const float ei = fexp2(pi);
                const float ef = fexp2(pf);
                const float eo = fexp2(po);
                const float eg = fexp2(pg);                      // |raw pg| < 18 -> no ovf
                const float f  = frcp(1.f + ef);
                const float ig = (eg - 1.f) * frcp((eg + 1.f) * (1.f + ei));
                const float cc = f * cst[ug * 4 + j] + ig;
                cst[ug * 4 + j] = cc;
                const float ec = fexp2(fminf(TWOL * cc, 126.f)); // c can grow -> clamp
                const float h  = (ec - 1.f) * frcp((ec + 1.f) * (1.f + eo));
                const int row  = l4 * 4 + j;
                const int unit = u0 + ug * 16 + l15;
                // lane-pair pack via quad_perm DPP (VALU, not DS) -> aligned b32 write
                const u32 hb = (u32)__builtin_bit_cast(u16, (_Float16)h);
                const u32 obp = (u32)__builtin_amdgcn_update_dpp(
                                    0, (int)hb, 0xB1 /*quad_perm [1,0,3,2]*/, 0xF, 0xF, true);
                if ((l15 & 1) == 0) {
                    const u32 packed = hb | (obp << 16);
                    const int idx = (unit >> 3) * 128 + row * 8 + (unit & 6);
                    *(u32*)(&hdst[idx]) = packed;
                }
            }
        }
        __syncthreads();   // h_{t+1} complete before the next step's reads
    };

    for (int t = 0; t < NT; t += 2) {
        step(t,     hA, hB);
        step(t + 1, hB, hA);
    }

    // ---- epilogue: h_T is in hA (t=511 wrote hA) ----
    if constexpr (FUSED) {
        half8 af[8];
        #pragma unroll
        for (int kc = 0; kc < 8; kc++)
            af[kc] = *(const half8*)(hA + (kc * 4 + l4) * 128 + l15 * 8);
        const int o0 = wv * 64;
        #pragma unroll
        for (int nt = 0; nt < 4; nt++) {
            const int col = o0 + nt * 16 + l15;
            floatx4 accL = (floatx4){0.f, 0.f, 0.f, 0.f};
            #pragma unroll
            for (int kc = 0; kc < 8; kc++) {
                const half8 b = *(const half8*)(WlinPack + (size_t)col * NH + kc * 32 + l4 * 8);
                accL = mfma16(af[kc], b, accL);
            }
            const float bb = blin[col];
            #pragma unroll
            for (int j = 0; j < 4; j++)
                outp[(size_t)(r0 + l4 * 4 + j) * NOUT + col] = accL[j] + bb;
        }
    } else {
        for (int i = tid; i < 4096; i += 512) {
            const int row = i >> 8, unit = i & 255;
            hlast[(size_t)(r0 + row) * NH + unit] =
                hA[(unit >> 3) * 128 + row * 8 + (unit & 7)];
        }
    }
}

// --------------------------------------------------- linear (fallback) ----
__global__ __launch_bounds__(256, 2)
void linear_kernel(const u16* __restrict__ hlast_u, const _Float16* __restrict__ WlinPack,
                   const float* __restrict__ blin, float* __restrict__ out)
{
    const int tid = threadIdx.x;
    const int lane = tid & 63;
    const int wv = tid >> 6;
    const int mi = wv >> 1, ni = wv & 1;
    const int l15 = lane & 15, l4 = lane >> 4;
    const int r0 = (blockIdx.x >> 3) * 32;
    const int o0 = (blockIdx.x & 7) * 64;
    const _Float16* hl = (const _Float16*)hlast_u;
    const int arow = r0 + mi * 16 + l15;

    half8 a[8];
    #pragma unroll
    for (int kc = 0; kc < 8; kc++)
        a[kc] = *(const half8*)(hl + (size_t)arow * NH + kc * 32 + l4 * 8);

    #pragma unroll
    for (int nt = 0; nt < 2; nt++) {
        const int col = o0 + ni * 32 + nt * 16 + l15;
        floatx4 acc = (floatx4){0.f, 0.f, 0.f, 0.f};
        #pragma unroll
        for (int kc = 0; kc < 8; kc++) {
            const half8 b = *(const half8*)(WlinPack + (size_t)col * NH + kc * 32 + l4 * 8);
            acc = mfma16(a[kc], b, acc);
        }
        const float bb = blin[col];
        #pragma unroll
        for (int j = 0; j < 4; j++) {
            const int row = r0 + mi * 16 + l4 * 4 + j;
            out[(size_t)row * NOUT + col] = acc[j] + bb;
        }
    }
}

// --------------------------------------------------------------- launch ----
extern "C" void kernel_launch(void* const* d_in, const int* in_sizes, int n_in,
                              void* d_out, int out_size, void* d_ws, size_t ws_size,
                              hipStream_t stream)
{
    const float* x    = (const float*)d_in[0];
    const float* Wih  = (const float*)d_in[1];
    const float* Whh  = (const float*)d_in[2];
    const float* bih  = (const float*)d_in[3];
    const float* bhh  = (const float*)d_in[4];
    const float* Wlin = (const float*)d_in[5];
    const float* blin = (const float*)d_in[6];

    char* ws = (char*)d_ws;
    _Float16* Wpack    = (_Float16*)(ws);                 // 512 KB
    _Float16* WlinPack = (_Float16*)(ws + (512 << 10));   // 256 KB

    const size_t need_fused = (768 << 10) + (size_t)NT * NB * 4;  // +4MB xT
    const bool fused = ws_size >= need_fused;

    if (fused) {
        float* xT = (float*)(ws + (768 << 10));
        prep_kernel<<<1280, 256, 0, stream>>>(x, Whh, Wlin, Wpack, WlinPack, xT);
        lstm_kernel<1><<<128, 512, 0, stream>>>(xT, Wih, bih, bhh, Wpack,
                                                WlinPack, blin, (float*)d_out, nullptr);
    } else {
        u16*   hlast = (u16*)(ws + (768 << 10));          // 1 MB
        float* xT    = (float*)d_out;                     // scratch until linear overwrites
        prep_kernel<<<1280, 256, 0, stream>>>(x, Whh, Wlin, Wpack, WlinPack, xT);
        lstm_kernel<0><<<128, 512, 0, stream>>>(xT, Wih, bih, bhh, Wpack,
                                                WlinPack, blin, nullptr, hlast);
        linear_kernel<<<512, 256, 0, stream>>>(hlast, WlinPack, blin, (float*)d_out);
    }
}

// Round 14
// 1065.301 us; speedup vs baseline: 2.2367x; 2.2367x over previous
//
#include <hip/hip_runtime.h>
#include <cstdint>

typedef _Float16 half8 __attribute__((ext_vector_type(8)));
typedef float floatx4 __attribute__((ext_vector_type(4)));
typedef unsigned long long u64;
typedef unsigned int u32;
typedef unsigned short u16;

#define NB 2048
#define NT 512
#define NH 256
#define NOUT 512

#define LOG2E 1.4426950408889634f
#define TWOL  2.8853900817779268f

__device__ __forceinline__ float fexp2(float x){ return __builtin_amdgcn_exp2f(x); }
__device__ __forceinline__ float frcp(float x){ return __builtin_amdgcn_rcpf(x); }

__device__ __forceinline__ floatx4 mfma16(half8 a, half8 b, floatx4 c) {
    return __builtin_amdgcn_mfma_f32_16x16x32_f16(a, b, c, 0, 0, 0);
}

// ----------------------------------------------------------------- prep ----
// blocks 0..1023: 32x32 transpose tiles of x -> xT ;  blocks 1024..1279: f16 packs.
// GATE-SCALE FOLDING (r12): rows 512..767 (g) x +2*LOG2E, others (i,f,o) x -LOG2E,
// so the pointwise computes exp2(p) directly.
__global__ void prep_kernel(const float* __restrict__ x, const float* __restrict__ Whh,
                            const float* __restrict__ Wlin, _Float16* __restrict__ Wpack,
                            _Float16* __restrict__ WlinPack, float* __restrict__ xT)
{
    const int b = blockIdx.x;
    if (b < 1024) {
        __shared__ float tile[32][33];
        const int tx = threadIdx.x & 31, ty = threadIdx.x >> 5;
        const int t0 = (b & 15) * 32;
        const int b0 = (b >> 4) * 32;
        #pragma unroll
        for (int i = 0; i < 4; i++)
            tile[ty + 8 * i][tx] = x[(size_t)(b0 + ty + 8 * i) * NT + t0 + tx];
        __syncthreads();
        #pragma unroll
        for (int i = 0; i < 4; i++)
            xT[(size_t)(t0 + ty + 8 * i) * NB + b0 + tx] = tile[tx][ty + 8 * i];
    } else {
        const int i = (b - 1024) * 256 + threadIdx.x;
        const int stride = 256 * 256;
        for (int k = i; k < 1024 * 256; k += stride) {
            const int row = k >> 8;
            const float s = (row >= 512 && row < 768) ? TWOL : -LOG2E;
            Wpack[k] = (_Float16)(s * Whh[k]);
        }
        for (int k = i; k < 512 * 256;  k += stride) WlinPack[k] = (_Float16)Wlin[k];
    }
}

// ----------------------------------------------------------------- lstm ----
// 128 blocks x 512 threads (8 waves, 2 waves/SIMD). Block: 16 rows, full 256 units.
// Wave wv: units [wv*32,+32) = 2 ug x 16 units x 4 gates; i,f,g register-resident
// (192 regs, unified V+A file); o-gate in LDS (16 tiles, 128 KB, K-major).
// K-major LDS h layout (r7, conflict-free b128); static ping-pong + 2-step
// unroll (r12); gate-scale folding (r12).
// r14 (register-neutral DS diet; r13 proved any extra liveness -> spill):
//   (a) lane^1 h-pack via quad_perm DPP (VALU) instead of __shfl_xor
//       (ds_bpermute): -8 DS instr/thread-step. Verified bit-identical in r13.
//   (b) bw packed layout: {bias,wih} x 4 gates contiguous per unit, stride 48B
//       (2-way bank alias = free): 8 ds_read_b64 -> 4 ds_read_b128 per step.
// FUSED=1: linear layer fused in epilogue from h_T (in hA after 512 steps).
template<int FUSED>
__global__ __launch_bounds__(512, 1)
void lstm_kernel(const float* __restrict__ xT, const float* __restrict__ Wih,
                 const float* __restrict__ bih, const float* __restrict__ bhh,
                 const _Float16* __restrict__ Wpack, const _Float16* __restrict__ WlinPack,
                 const float* __restrict__ blin, float* __restrict__ outp,
                 u16* __restrict__ hlast)
{
    __shared__ __align__(16) u16 wlds[16][4096];   // 128 KB o-gate tiles (K-major)
    __shared__ __align__(16) u16 hA[4096];         // 8 KB  h (even t source)
    __shared__ __align__(16) u16 hB[4096];         // 8 KB  h (odd t source)
    __shared__ __align__(16) float bwq[256 * 12];  // 12 KB {bias,wih}x4 per unit, stride 48B

    const int tid  = threadIdx.x;
    const int lane = tid & 63;
    const int wv   = tid >> 6;     // 0..7
    const int l15  = lane & 15;
    const int l4   = lane >> 4;
    const int r0   = blockIdx.x * 16;
    const int u0   = wv * 32;

    // ---- prologue ----
    for (int g = tid; g < 1024; g += 512) {
        const int q = g >> 8, u = g & 255;
        const float s = (q == 2) ? TWOL : -LOG2E;
        bwq[u * 12 + q * 2]     = s * (bih[g] + bhh[g]);
        bwq[u * 12 + q * 2 + 1] = s * Wih[g];
    }
    for (int i = tid; i < 1024; i += 512) ((u64*)hA)[i] = 0;   // h_0 = 0

    // stage o-gate tiles into LDS, K-major: dest = kchunk*128 + row*8
    for (int ch = tid; ch < 8192; ch += 512) {
        const int tl = ch >> 9;            // tile 0..15 (= wv*2+ug)
        const int cc = ch & 511;
        const int row = cc >> 5;           // unit row in tile 0..15
        const int kch = cc & 31;           // 8-elem K chunk 0..31
        const int G  = 768 + (tl >> 1) * 32 + (tl & 1) * 16 + row;
        half8 v = *(const half8*)(Wpack + (size_t)G * NH + kch * 8);
        *(half8*)(&wlds[tl][kch * 128 + row * 8]) = v;
    }

    // register-resident W tiles: ug x {i,f,g}
    half8 wreg[2][3][8];
    #pragma unroll
    for (int ug = 0; ug < 2; ug++)
        #pragma unroll
        for (int q = 0; q < 3; q++) {
            const int G = q * 256 + u0 + ug * 16 + l15;
            #pragma unroll
            for (int kc = 0; kc < 8; kc++)
                wreg[ug][q][kc] = *(const half8*)(Wpack + (size_t)G * NH + kc * 32 + l4 * 8);
        }

    float cst[8];
    #pragma unroll
    for (int i = 0; i < 8; i++) cst[i] = 0.f;

    __syncthreads();

    // one timestep: read hsrc, write hdst (distinct static arrays per call site)
    auto step = [&](int t, const u16* hsrc, u16* hdst) {
        // issued at step head, consumed only in the pointwise tails
        const floatx4 xv = *(const floatx4*)(xT + (size_t)t * NB + r0 + l4 * 4);

        #pragma unroll
        for (int ug = 0; ug < 2; ug++) {
            floatx4 acc[4];
            #pragma unroll
            for (int q = 0; q < 4; q++)
                acc[q] = (floatx4){0.f, 0.f, 0.f, 0.f};

            __builtin_amdgcn_s_setprio(1);
            #pragma unroll
            for (int half_ = 0; half_ < 2; half_++) {
                half8 a[4];
                #pragma unroll
                for (int k2 = 0; k2 < 4; k2++) {
                    const int kc = half_ * 4 + k2;
                    a[k2] = *(const half8*)(hsrc + (kc * 4 + l4) * 128 + l15 * 8);
                }
                #pragma unroll
                for (int k2 = 0; k2 < 4; k2++) {
                    const int kc = half_ * 4 + k2;
                    const half8 b3 = *(const half8*)(&wlds[wv * 2 + ug][(kc * 4 + l4) * 128 + l15 * 8]);
                    acc[0] = mfma16(a[k2], wreg[ug][0][kc], acc[0]);
                    acc[1] = mfma16(a[k2], wreg[ug][1][kc], acc[1]);
                    acc[2] = mfma16(a[k2], wreg[ug][2][kc], acc[2]);
                    acc[3] = mfma16(a[k2], b3,              acc[3]);
                }
            }
            __builtin_amdgcn_s_setprio(0);

            // scaled bias + x*W_ih in the tail (2x b128 packed reads); exp2(p) direct
            const float* bwp = bwq + (u0 + ug * 16 + l15) * 12;
            const floatx4 r01 = *(const floatx4*)(bwp);      // {b_i, w_i, b_f, w_f}
            const floatx4 r23 = *(const floatx4*)(bwp + 4);  // {b_g, w_g, b_o, w_o}

            #pragma unroll
            for (int j = 0; j < 4; j++) {
                const float pi = acc[0][j] + r01[0] + xv[j] * r01[1];  // = -LOG2E * raw
                const float pf = acc[1][j] + r01[2] + xv[j] * r01[3];
                const float pg = acc[2][j] + r23[0] + xv[j] * r23[1];  // = +TWOL * raw
                const float po = acc[3][j] + r23[2] + xv[j] * r23[3];
                const float ei = fexp2(pi);
                const float ef = fexp2(pf);
                const float eo = fexp2(po);
                const float eg = fexp2(pg);                      // |raw pg| < 18 -> no ovf
                const float f  = frcp(1.f + ef);
                const float ig = (eg - 1.f) * frcp((eg + 1.f) * (1.f + ei));
                const float cc = f * cst[ug * 4 + j] + ig;
                cst[ug * 4 + j] = cc;
                const float ec = fexp2(fminf(TWOL * cc, 126.f)); // c can grow -> clamp
                const float h  = (ec - 1.f) * frcp((ec + 1.f) * (1.f + eo));
                const int row  = l4 * 4 + j;
                const int unit = u0 + ug * 16 + l15;
                // lane-pair pack via quad_perm DPP (VALU, not DS) -> aligned b32 write
                const u32 hb = (u32)__builtin_bit_cast(u16, (_Float16)h);
                const u32 obp = (u32)__builtin_amdgcn_update_dpp(
                                    0, (int)hb, 0xB1 /*quad_perm [1,0,3,2]*/, 0xF, 0xF, true);
                if ((l15 & 1) == 0) {
                    const u32 packed = hb | (obp << 16);
                    const int idx = (unit >> 3) * 128 + row * 8 + (unit & 6);
                    *(u32*)(&hdst[idx]) = packed;
                }
            }
        }
        __syncthreads();   // h_{t+1} complete before the next step's reads
    };

    for (int t = 0; t < NT; t += 2) {
        step(t,     hA, hB);
        step(t + 1, hB, hA);
    }

    // ---- epilogue: h_T is in hA (t=511 wrote hA) ----
    if constexpr (FUSED) {
        half8 af[8];
        #pragma unroll
        for (int kc = 0; kc < 8; kc++)
            af[kc] = *(const half8*)(hA + (kc * 4 + l4) * 128 + l15 * 8);
        const int o0 = wv * 64;
        #pragma unroll
        for (int nt = 0; nt < 4; nt++) {
            const int col = o0 + nt * 16 + l15;
            floatx4 accL = (floatx4){0.f, 0.f, 0.f, 0.f};
            #pragma unroll
            for (int kc = 0; kc < 8; kc++) {
                const half8 b = *(const half8*)(WlinPack + (size_t)col * NH + kc * 32 + l4 * 8);
                accL = mfma16(af[kc], b, accL);
            }
            const float bb = blin[col];
            #pragma unroll
            for (int j = 0; j < 4; j++)
                outp[(size_t)(r0 + l4 * 4 + j) * NOUT + col] = accL[j] + bb;
        }
    } else {
        for (int i = tid; i < 4096; i += 512) {
            const int row = i >> 8, unit = i & 255;
            hlast[(size_t)(r0 + row) * NH + unit] =
                hA[(unit >> 3) * 128 + row * 8 + (unit & 7)];
        }
    }
}

// --------------------------------------------------- linear (fallback) ----
__global__ __launch_bounds__(256, 2)
void linear_kernel(const u16* __restrict__ hlast_u, const _Float16* __restrict__ WlinPack,
                   const float* __restrict__ blin, float* __restrict__ out)
{
    const int tid = threadIdx.x;
    const int lane = tid & 63;
    const int wv = tid >> 6;
    const int mi = wv >> 1, ni = wv & 1;
    const int l15 = lane & 15, l4 = lane >> 4;
    const int r0 = (blockIdx.x >> 3) * 32;
    const int o0 = (blockIdx.x & 7) * 64;
    const _Float16* hl = (const _Float16*)hlast_u;
    const int arow = r0 + mi * 16 + l15;

    half8 a[8];
    #pragma unroll
    for (int kc = 0; kc < 8; kc++)
        a[kc] = *(const half8*)(hl + (size_t)arow * NH + kc * 32 + l4 * 8);

    #pragma unroll
    for (int nt = 0; nt < 2; nt++) {
        const int col = o0 + ni * 32 + nt * 16 + l15;
        floatx4 acc = (floatx4){0.f, 0.f, 0.f, 0.f};
        #pragma unroll
        for (int kc = 0; kc < 8; kc++) {
            const half8 b = *(const half8*)(WlinPack + (size_t)col * NH + kc * 32 + l4 * 8);
            acc = mfma16(a[kc], b, acc);
        }
        const float bb = blin[col];
        #pragma unroll
        for (int j = 0; j < 4; j++) {
            const int row = r0 + mi * 16 + l4 * 4 + j;
            out[(size_t)row * NOUT + col] = acc[j] + bb;
        }
    }
}

// --------------------------------------------------------------- launch ----
extern "C" void kernel_launch(void* const* d_in, const int* in_sizes, int n_in,
                              void* d_out, int out_size, void* d_ws, size_t ws_size,
                              hipStream_t stream)
{
    const float* x    = (const float*)d_in[0];
    const float* Wih  = (const float*)d_in[1];
    const float* Whh  = (const float*)d_in[2];
    const float* bih  = (const float*)d_in[3];
    const float* bhh  = (const float*)d_in[4];
    const float* Wlin = (const float*)d_in[5];
    const float* blin = (const float*)d_in[6];

    char* ws = (char*)d_ws;
    _Float16* Wpack    = (_Float16*)(ws);                 // 512 KB
    _Float16* WlinPack = (_Float16*)(ws + (512 << 10));   // 256 KB

    const size_t need_fused = (768 << 10) + (size_t)NT * NB * 4;  // +4MB xT
    const bool fused = ws_size >= need_fused;

    if (fused) {
        float* xT = (float*)(ws + (768 << 10));
        prep_kernel<<<1280, 256, 0, stream>>>(x, Whh, Wlin, Wpack, WlinPack, xT);
        lstm_kernel<1><<<128, 512, 0, stream>>>(xT, Wih, bih, bhh, Wpack,
                                                WlinPack, blin, (float*)d_out, nullptr);
    } else {
        u16*   hlast = (u16*)(ws + (768 << 10));          // 1 MB
        float* xT    = (float*)d_out;                     // scratch until linear overwrites
        prep_kernel<<<1280, 256, 0, stream>>>(x, Whh, Wlin, Wpack, WlinPack, xT);
        lstm_kernel<0><<<128, 512, 0, stream>>>(xT, Wih, bih, bhh, Wpack,
                                                WlinPack, blin, nullptr, hlast);
        linear_kernel<<<512, 256, 0, stream>>>(hlast, WlinPack, blin, (float*)d_out);
    }
}